// Round 13
// baseline (141.793 us; speedup 1.0000x reference)
//
#include <hip/hip_runtime.h>
#include <cstdint>

// CapsuleLayer dynamic routing: B=256, R=1152, C=10, O=16, I=8, 3 iters.
// Round 13: ABLATION KERNEL (r12 + duplicated phase 1).
//  * r4-r12 ledger: 59us invariant to VALU issue, occupancy, conflicts,
//    scratch, per-CU bytes, barriers. Six nulls = stop guessing, ablate
//    (guide Common-mistake #8 / m164 lesson).
//  * This kernel re-runs the ENTIRE phase-1 loop a second time with
//    asm-laundered W/x pointers (no CSE), storing the SAME bf16 words to
//    the SAME LDS addresses (output bit-identical; passes). Dup s-sums
//    kept alive via asm volatile (rule #17: no DCE).
//  * READ: dur 59->78-84 => phase-1-throughput-bound (next: bf16/MFMA
//    phase-1 rewrite). dur 59-><=64 => phase 1 hidden, phase 2 binds.
//    WRITE_SIZE must stay ~0.16MB (no spill); absmax 0.007324 unchanged.
#define BB 256
#define RR 1152
#define CC 10
#define OO 16
#define II 8
#define NT 768
#define GG 2
#define NWAVE (NT / 64)    // 12
#define WPG (NWAVE / GG)   // 6 waves per g in phase 2
#define LOG2E 1.4426950408889634f

typedef float float2v __attribute__((ext_vector_type(2)));

__device__ __forceinline__ void unpack2(uint32_t pk, float& lo, float& hi) {
    union { uint32_t i; float f; } a, b;
    a.i = pk << 16; b.i = pk & 0xffff0000u;
    lo = a.f; hi = b.f;
}
__device__ __forceinline__ float dot4pk(float4 a, float4 b) {
    float2v al = { a.x, a.y }, ah = { a.z, a.w };
    float2v bl = { b.x, b.y }, bh = { b.z, b.w };
    float2v h = __builtin_elementwise_fma(ah, bh, al * bl);
    return h.x + h.y;
}
__device__ __forceinline__ float qpadd1(float v) {
    int o = __builtin_amdgcn_mov_dpp(__float_as_int(v), 0xB1, 0xF, 0xF, true);
    return v + __int_as_float(o);
}
__device__ __forceinline__ float qpadd2(float v) {
    int o = __builtin_amdgcn_mov_dpp(__float_as_int(v), 0x4E, 0xF, 0xF, true);
    return v + __int_as_float(o);
}
__device__ __forceinline__ float dppx2f(float v) {
    return __int_as_float(__builtin_amdgcn_mov_dpp(__float_as_int(v), 0x4E, 0xF, 0xF, true));
}
__device__ __forceinline__ uint32_t cvtpk(float lo, float hi) {
    uint32_t r;
    asm("v_cvt_pk_bf16_f32 %0, %1, %2" : "=v"(r) : "v"(lo), "v"(hi));
    return r;
}
#if __has_builtin(__builtin_amdgcn_exp2f)
#define EXP2(x) __builtin_amdgcn_exp2f(x)
#else
#define EXP2(x) __expf((x) * 0.6931471805599453f)
#endif
#define LD4(P) (*reinterpret_cast<const float4*>(P))

#define P1G(XV, SG0, SG1, SG2, SG3, WR)                                       \
  do {                                                                        \
    float d0 = qpadd1(dot4pk(w0, XV));                                        \
    float d1 = qpadd1(dot4pk(w1, XV));                                        \
    float d2 = qpadd1(dot4pk(w2, XV));                                        \
    float d3 = qpadd1(dot4pk(w3, XV));                                        \
    SG0 += d0; SG1 += d1; SG2 += d2; SG3 += d3;                               \
    float sa = pb1 ? (pb0 ? d3 : d2) : (pb0 ? d1 : d0);                       \
    float sb = pb1 ? (pb0 ? d1 : d0) : (pb0 ? d3 : d2);                       \
    (WR)[(size_t)it * 768] = cvtpk(sa, dppx2f(sb));                           \
  } while (0)

__global__ __launch_bounds__(NT, 6)
void k_caps(const float* __restrict__ x, const float* __restrict__ W,
            float* __restrict__ out) {
    extern __shared__ uint32_t u2[];          // [GG][RR][8] packed bf16 pairs
    __shared__ float p0s[NWAVE][8][4][GG];
    __shared__ float part2[2][17][NWAVE];

    const int t = threadIdx.x;
    const int c  = blockIdx.x / (BB / GG);
    const int b0 = (blockIdx.x % (BB / GG)) * GG;
    const int wv = t >> 6, l = t & 63;
    const int rg = t >> 3, p = t & 7;

    uint32_t* uA = u2;
    uint32_t* uB = u2 + (size_t)RR * 8;

    const int pos = (p >> 1) + ((p & 1) << 2);
    uint32_t* wrA = uA + (size_t)rg * 8 + pos;
    uint32_t* wrB = uB + (size_t)rg * 8 + pos;
    const bool pb0 = (p & 1) != 0, pb1 = (p & 2) != 0;

    // ---- Phase 1 (real) ----
    float s00 = 0.f, s01 = 0.f, s02 = 0.f, s03 = 0.f;
    float s10 = 0.f, s11 = 0.f, s12 = 0.f, s13 = 0.f;
#pragma unroll 2
    for (int it = 0; it < 12; ++it) {
        const int r = it * 96 + rg;
        const float* wrow = W + ((size_t)r * CC + c) * (OO * II) + p * 4;
        float4 w0 = LD4(wrow);
        float4 w1 = LD4(wrow + 32);
        float4 w2 = LD4(wrow + 64);
        float4 w3 = LD4(wrow + 96);
        const float* xp = x + ((size_t)b0 * RR + r) * II + (p & 1) * 4;
        float4 xa = LD4(xp);
        float4 xb = LD4(xp + (size_t)RR * II);
        P1G(xa, s00, s01, s02, s03, wrA);
        P1G(xb, s10, s11, s12, s13, wrB);
    }
#pragma unroll
    for (int m = 8; m < 64; m <<= 1) {
        s00 += __shfl_xor(s00, m); s01 += __shfl_xor(s01, m);
        s02 += __shfl_xor(s02, m); s03 += __shfl_xor(s03, m);
        s10 += __shfl_xor(s10, m); s11 += __shfl_xor(s11, m);
        s12 += __shfl_xor(s12, m); s13 += __shfl_xor(s13, m);
    }
    if (l < 8) {
        p0s[wv][l][0][0] = s00; p0s[wv][l][1][0] = s01;
        p0s[wv][l][2][0] = s02; p0s[wv][l][3][0] = s03;
        p0s[wv][l][0][1] = s10; p0s[wv][l][1][1] = s11;
        p0s[wv][l][2][1] = s12; p0s[wv][l][3][1] = s13;
    }

    // ===== ABLATION: phase 1 duplicated (laundered ptrs, same stores) =====
    {
        uint64_t wbits = (uint64_t)W, xbits = (uint64_t)x;
        asm volatile("" : "+v"(wbits), "+v"(xbits));   // opaque: no CSE
        const float* Wd = (const float*)wbits;
        const float* xd = (const float*)xbits;
        float z00 = 0.f, z01 = 0.f, z02 = 0.f, z03 = 0.f;
        float z10 = 0.f, z11 = 0.f, z12 = 0.f, z13 = 0.f;
#pragma unroll 2
        for (int it = 0; it < 12; ++it) {
            const int r = it * 96 + rg;
            const float* wrow = Wd + ((size_t)r * CC + c) * (OO * II) + p * 4;
            float4 w0 = LD4(wrow);
            float4 w1 = LD4(wrow + 32);
            float4 w2 = LD4(wrow + 64);
            float4 w3 = LD4(wrow + 96);
            const float* xp = xd + ((size_t)b0 * RR + r) * II + (p & 1) * 4;
            float4 xa = LD4(xp);
            float4 xb = LD4(xp + (size_t)RR * II);
            P1G(xa, z00, z01, z02, z03, wrA);   // same values, same addrs
            P1G(xb, z10, z11, z12, z13, wrB);
        }
        asm volatile("" :: "v"(z00), "v"(z01), "v"(z02), "v"(z03),
                           "v"(z10), "v"(z11), "v"(z12), "v"(z13));
    }
    __syncthreads();                          // BARRIER 1 of 3

    // ---- Phase-2 mapping (r12 unchanged) ----
    const int g2 = wv / WPG;
    const int wv6 = wv - g2 * WPG;
    const uint32_t* ug = g2 ? uB : uA;
    const int q = l & 3;
    const int rl = l >> 2;
    const int rbase = wv6 * 16 + rl;
    const uint32_t* rp = ug + (size_t)rbase * 8 + 2 * q;

    const int oo = l & 15;
    const int gb = l & 48;
    const int t0 = gb | (2 * q), t1 = gb | (2 * q + 1);
    const int t2 = gb | (2 * q + 8), t3 = gb | (2 * q + 9);

    float ra, rb, rc, rd;
    {
        float sv = 0.f;
#pragma unroll
        for (int w = 0; w < NWAVE; ++w) sv += p0s[w][2 * (oo & 3)][oo >> 2][g2];
        sv *= (1.0f / RR);
        float ss = sv * sv;
        ss += __shfl_xor(ss, 1); ss += __shfl_xor(ss, 2);
        ss += __shfl_xor(ss, 4); ss += __shfl_xor(ss, 8);
        float vv = sv * (ss / ((1.0f + ss) * sqrtf(ss + 1e-7f)));
        ra = __shfl(vv, t0); rb = __shfl(vv, t1);
        rc = __shfl(vv, t2); rd = __shfl(vv, t3);
    }

#pragma unroll
    for (int pass = 1; pass < 3; ++pass) {
        const float2v WQA = { ra * LOG2E, rc * LOG2E };
        const float2v WQB = { rb * LOG2E, rd * LOG2E };
        float2v N0 = { 0.f, 0.f }, N1 = { 0.f, 0.f };
        float den = 0.f;

#pragma unroll
        for (int it2 = 0; it2 < 12; ++it2) {
            uint2 pp = *reinterpret_cast<const uint2*>(rp + (size_t)it2 * 768);
            float u0, u1, u2f, u3;
            unpack2(pp.x, u0, u1);
            unpack2(pp.y, u3, u2f);
            float2v P0 = { u0, u2f };
            float2v P1 = { u1, u3 };
            float2v lg2 = __builtin_elementwise_fma(P0, WQA, P1 * WQB);
            float lg = lg2.x + lg2.y;
            lg = qpadd1(lg);
            lg = qpadd2(lg);
            float e = EXP2(lg);
            den += e;
            float2v E2 = { e, e };
            N0 = __builtin_elementwise_fma(E2, P0, N0);
            N1 = __builtin_elementwise_fma(E2, P1, N1);
        }

        float n0 = N0.x, n2 = N0.y, n1 = N1.x, n3 = N1.y;
#pragma unroll
        for (int m = 4; m < 64; m <<= 1) {
            n0 += __shfl_xor(n0, m); n1 += __shfl_xor(n1, m);
            n2 += __shfl_xor(n2, m); n3 += __shfl_xor(n3, m);
            den += __shfl_xor(den, m);
        }
        const int pb = pass & 1;
        if (l < 4) {
            part2[pb][2 * l][wv]     = n0;
            part2[pb][2 * l + 1][wv] = n1;
            part2[pb][2 * l + 8][wv] = n2;
            part2[pb][2 * l + 9][wv] = n3;
            if (l == 0) part2[pb][16][wv] = den;
        }
        __syncthreads();                      // BARRIERS 2,3

        const float* po = &part2[pb][oo][0];
        const float* pd = &part2[pb][16][0];
        float nf = 0.f, df = 0.f;
#pragma unroll
        for (int w = 0; w < WPG; ++w) {
            nf += po[g2 * WPG + w];
            df += pd[g2 * WPG + w];
        }
        float s2 = nf / df;
        float ss2 = s2 * s2;
        ss2 += __shfl_xor(ss2, 1); ss2 += __shfl_xor(ss2, 2);
        ss2 += __shfl_xor(ss2, 4); ss2 += __shfl_xor(ss2, 8);
        float vv2 = s2 * (ss2 / ((1.0f + ss2) * sqrtf(ss2 + 1e-7f)));

        if (pass == 1) {
            ra += __shfl(vv2, t0); rb += __shfl(vv2, t1);
            rc += __shfl(vv2, t2); rd += __shfl(vv2, t3);
        } else {
            if ((wv == 0 || wv == WPG) && l < 16)
                out[((size_t)(b0 + g2) * CC + c) * OO + oo] = vv2;
        }
    }
}

extern "C" void kernel_launch(void* const* d_in, const int* in_sizes, int n_in,
                              void* d_out, int out_size, void* d_ws, size_t ws_size,
                              hipStream_t stream) {
    const float* x = (const float*)d_in[0];  // (B,R,I) fp32
    const float* W = (const float*)d_in[1];  // (R,C,O,I) fp32
    if (n_in >= 2 && in_sizes[0] == RR * CC * OO * II &&
        in_sizes[1] == BB * RR * II) {
        const float* tmp = x; x = W; W = tmp;
    }
    float* out = (float*)d_out;              // (B,1,C,O,1) fp32

    const size_t dyn_lds = (size_t)GG * RR * 8 * 4;   // 73,728 B
    k_caps<<<CC * (BB / GG), NT, dyn_lds, stream>>>(x, W, out);
}

// Round 14
// 110.209 us; speedup vs baseline: 1.2866x; 1.2866x over previous
//
#include <hip/hip_runtime.h>
#include <cstdint>

// CapsuleLayer dynamic routing: B=256, R=1152, C=10, O=16, I=8, 3 iters.
// Round 14: attack phase-1 ingest (r13 ablation: phase 1 = 37.5us of 59,
// of which ~25us is the W/x line-request stream, ~10us VALU).
//  * PRE-PASS kernel converts W -> packed bf16 pairs in d_ws (2.95MB,
//    ~3us, once per launch). W row (r,c) = 256B: phase-1 W loads drop
//    64 -> 32 lines/wave-iter; W bytes/block 576 -> 288KB.
//  * New phase-1 mapping: lane p loads o=p and o=p+8 ENTIRELY (uint4 at
//    word 4p and 32+4p of the row; 8 lanes = 128B contiguous/instr).
//    Full dot in-lane (pk_fma chain over 4 bf16-pairs vs fp32 x pairs);
//    store = ONE cvtpk(d_p, d_{p+8}) -> word p. NO dpp/select packing.
//    LDS word k of row = (u[o=k], u[o=k+8]) -> phase-2 P0/P1 unpack is
//    direct (swapped-row trick deleted). Bank: word = lane id -> 2-way.
//  * Phase 2 / barrier structure = r12 (3 barriers, redundant squash,
//    weights in regs). Dots fp32; only W is bf16-rounded -> absmax
//    expected ~0.008-0.011 vs threshold 0.0172 (gating risk; revert if
//    fail).
#define BB 256
#define RR 1152
#define CC 10
#define OO 16
#define II 8
#define NT 768
#define GG 2
#define NWAVE (NT / 64)    // 12
#define WPG (NWAVE / GG)   // 6 waves per g in phase 2
#define LOG2E 1.4426950408889634f
#define WSWORDS ((size_t)RR * CC * (OO * II / 2))   // 737280 packed words

typedef float float2v __attribute__((ext_vector_type(2)));

__device__ __forceinline__ void unpack2(uint32_t pk, float& lo, float& hi) {
    union { uint32_t i; float f; } a, b;
    a.i = pk << 16; b.i = pk & 0xffff0000u;
    lo = a.f; hi = b.f;
}
// v + (value from lane l^1), DPP quad_perm [1,0,3,2] — VALU pipe
__device__ __forceinline__ float qpadd1(float v) {
    int o = __builtin_amdgcn_mov_dpp(__float_as_int(v), 0xB1, 0xF, 0xF, true);
    return v + __int_as_float(o);
}
// v + (value from lane l^2), DPP quad_perm [2,3,0,1]
__device__ __forceinline__ float qpadd2(float v) {
    int o = __builtin_amdgcn_mov_dpp(__float_as_int(v), 0x4E, 0xF, 0xF, true);
    return v + __int_as_float(o);
}
// packed bf16 pair from two f32 (hardware RNE), one instruction
__device__ __forceinline__ uint32_t cvtpk(float lo, float hi) {
    uint32_t r;
    asm("v_cvt_pk_bf16_f32 %0, %1, %2" : "=v"(r) : "v"(lo), "v"(hi));
    return r;
}
#if __has_builtin(__builtin_amdgcn_exp2f)
#define EXP2(x) __builtin_amdgcn_exp2f(x)
#else
#define EXP2(x) __expf((x) * 0.6931471805599453f)
#endif
#define LD4(P) (*reinterpret_cast<const float4*>(P))

// full 8-dot: 4 packed pairs of W vs 4 packed pairs of x, pk chain + hadd
#define DOT8(PA0, PA1, PA2, PA3, X0, X1, X2, X3, OUT)                         \
  do {                                                                        \
    float2v acc_ = PA0 * X0;                                                  \
    acc_ = __builtin_elementwise_fma(PA1, X1, acc_);                          \
    acc_ = __builtin_elementwise_fma(PA2, X2, acc_);                          \
    acc_ = __builtin_elementwise_fma(PA3, X3, acc_);                          \
    OUT = acc_.x + acc_.y;                                                    \
  } while (0)

#define UNPK(WQ, P0, P1, P2, P3)                                              \
  do {                                                                        \
    float lo_, hi_;                                                           \
    unpack2(WQ.x, lo_, hi_); P0 = (float2v){lo_, hi_};                        \
    unpack2(WQ.y, lo_, hi_); P1 = (float2v){lo_, hi_};                        \
    unpack2(WQ.z, lo_, hi_); P2 = (float2v){lo_, hi_};                        \
    unpack2(WQ.w, lo_, hi_); P3 = (float2v){lo_, hi_};                        \
  } while (0)

// ---- pre-pass: W fp32 -> packed bf16 pairs (same element order) ----
__global__ __launch_bounds__(256)
void k_cvt(const float* __restrict__ Wf, uint32_t* __restrict__ wbf) {
    size_t i = ((size_t)blockIdx.x * 256 + threadIdx.x) * 4;  // word index
    if (i < WSWORDS) {
        float4 a = LD4(Wf + 2 * i);
        float4 b = LD4(Wf + 2 * i + 4);
        uint4 r;
        r.x = cvtpk(a.x, a.y); r.y = cvtpk(a.z, a.w);
        r.z = cvtpk(b.x, b.y); r.w = cvtpk(b.z, b.w);
        *reinterpret_cast<uint4*>(wbf + i) = r;
    }
}

__global__ __launch_bounds__(NT, 6)
void k_caps(const float* __restrict__ x, const uint32_t* __restrict__ wb,
            float* __restrict__ out) {
    extern __shared__ uint32_t u2[];          // [GG][RR][8] packed bf16 pairs
    __shared__ float p0s[NWAVE][8][2][GG];    // [wv][p][slot o>>3][g]
    __shared__ float part2[2][17][NWAVE];

    const int t = threadIdx.x;
    const int c  = blockIdx.x / (BB / GG);    // c-major: blocks share W-slice
    const int b0 = (blockIdx.x % (BB / GG)) * GG;
    const int wv = t >> 6, l = t & 63;
    const int rg = t >> 3, p = t & 7;         // phase 1: 96 r-rows x 8 lanes

    uint32_t* uA = u2;                        // batch b0
    uint32_t* uB = u2 + (size_t)RR * 8;       // batch b0+1
    uint32_t* wrA = uA + (size_t)rg * 8 + p;  // word p of row rg
    uint32_t* wrB = uB + (size_t)rg * 8 + p;

    // ---- Phase 1: lane p computes u[o=p], u[o=p+8] for both g ----
    float s00 = 0.f, s01 = 0.f, s10 = 0.f, s11 = 0.f;
#pragma unroll 2
    for (int it = 0; it < 12; ++it) {
        const int r = it * 96 + rg;
        const uint32_t* wrow = wb + ((size_t)r * CC + c) * 64 + 4 * p;
        uint4 wq0 = *reinterpret_cast<const uint4*>(wrow);        // o = p
        uint4 wq1 = *reinterpret_cast<const uint4*>(wrow + 32);   // o = p+8
        const float* xp = x + ((size_t)b0 * RR + r) * II;
        float4 xa0 = LD4(xp);
        float4 xa1 = LD4(xp + 4);
        float4 xg0 = LD4(xp + (size_t)RR * II);
        float4 xg1 = LD4(xp + (size_t)RR * II + 4);
        float2v A0, A1, A2, A3, B0, B1, B2, B3;
        UNPK(wq0, A0, A1, A2, A3);
        UNPK(wq1, B0, B1, B2, B3);
        float2v X0 = { xa0.x, xa0.y }, X1 = { xa0.z, xa0.w };
        float2v X2 = { xa1.x, xa1.y }, X3 = { xa1.z, xa1.w };
        float2v Y0 = { xg0.x, xg0.y }, Y1 = { xg0.z, xg0.w };
        float2v Y2 = { xg1.x, xg1.y }, Y3 = { xg1.z, xg1.w };
        float d0, d1, e0, e1;
        DOT8(A0, A1, A2, A3, X0, X1, X2, X3, d0);   // g=0, o=p
        DOT8(B0, B1, B2, B3, X0, X1, X2, X3, d1);   // g=0, o=p+8
        DOT8(A0, A1, A2, A3, Y0, Y1, Y2, Y3, e0);   // g=1, o=p
        DOT8(B0, B1, B2, B3, Y0, Y1, Y2, Y3, e1);   // g=1, o=p+8
        s00 += d0; s01 += d1; s10 += e0; s11 += e1;
        wrA[(size_t)it * 768] = cvtpk(d0, d1);      // word p = (u[p], u[p+8])
        wrB[(size_t)it * 768] = cvtpk(e0, e1);
    }
    // pass-0 reduce over the 8 row-lanes sharing p (masks 8,16,32)
#pragma unroll
    for (int m = 8; m < 64; m <<= 1) {
        s00 += __shfl_xor(s00, m); s01 += __shfl_xor(s01, m);
        s10 += __shfl_xor(s10, m); s11 += __shfl_xor(s11, m);
    }
    if (l < 8) {                              // lane l == p
        p0s[wv][l][0][0] = s00; p0s[wv][l][1][0] = s01;
        p0s[wv][l][0][1] = s10; p0s[wv][l][1][1] = s11;
    }
    __syncthreads();                          // BARRIER 1 of 3

    // ---- Phase-2 mapping (r12 structure) ----
    const int g2 = wv / WPG;                  // waves 0-5: g=0, 6-11: g=1
    const int wv6 = wv - g2 * WPG;
    const uint32_t* ug = g2 ? uB : uA;
    const int q = l & 3;                      // owns o in {2q,2q+1,2q+8,2q+9}
    const int rl = l >> 2;
    const int rbase = wv6 * 16 + rl;
    const uint32_t* rp = ug + (size_t)rbase * 8 + 2 * q;

    const int oo = l & 15;                    // lane's redundant-squash o
    const int gb = l & 48;
    const int t0 = gb | (2 * q), t1 = gb | (2 * q + 1);
    const int t2 = gb | (2 * q + 8), t3 = gb | (2 * q + 9);

    // ---- v0 computed redundantly by all lanes ----
    float ra, rb, rc, rd;
    {
        float sv = 0.f;
#pragma unroll
        for (int w = 0; w < NWAVE; ++w) sv += p0s[w][oo & 7][oo >> 3][g2];
        sv *= (1.0f / RR);                    // softmax(0) = 1/R
        float ss = sv * sv;
        ss += __shfl_xor(ss, 1); ss += __shfl_xor(ss, 2);
        ss += __shfl_xor(ss, 4); ss += __shfl_xor(ss, 8);
        float vv = sv * (ss / ((1.0f + ss) * sqrtf(ss + 1e-7f)));
        ra = __shfl(vv, t0); rb = __shfl(vv, t1);
        rc = __shfl(vv, t2); rd = __shfl(vv, t3);
    }

    // ---- Phase 2: passes 1 and 2; one barrier each ----
#pragma unroll
    for (int pass = 1; pass < 3; ++pass) {
        const float2v WQA = { ra * LOG2E, rc * LOG2E };
        const float2v WQB = { rb * LOG2E, rd * LOG2E };
        float2v N0 = { 0.f, 0.f }, N1 = { 0.f, 0.f };
        float den = 0.f;

#pragma unroll
        for (int it2 = 0; it2 < 12; ++it2) {
            uint2 pp = *reinterpret_cast<const uint2*>(rp + (size_t)it2 * 768);
            float a_, b_, c_, d_;
            unpack2(pp.x, a_, b_);            // (u[2q],   u[2q+8])
            unpack2(pp.y, c_, d_);            // (u[2q+1], u[2q+9])
            float2v P0 = { a_, b_ };
            float2v P1 = { c_, d_ };
            float2v lg2 = __builtin_elementwise_fma(P0, WQA, P1 * WQB);
            float lg = lg2.x + lg2.y;
            lg = qpadd1(lg);                  // + lane^1 (quad partial)
            lg = qpadd2(lg);                  // + lane^2: full 16-o logit
            float e = EXP2(lg);               // == exp(raw logit)
            den += e;                         // same-q lanes: distinct r's
            float2v E2 = { e, e };
            N0 = __builtin_elementwise_fma(E2, P0, N0);
            N1 = __builtin_elementwise_fma(E2, P1, N1);
        }

        float n0 = N0.x, n2 = N0.y, n1 = N1.x, n3 = N1.y;
#pragma unroll
        for (int m = 4; m < 64; m <<= 1) {    // 16 same-q lanes: distinct rows
            n0 += __shfl_xor(n0, m); n1 += __shfl_xor(n1, m);
            n2 += __shfl_xor(n2, m); n3 += __shfl_xor(n3, m);
            den += __shfl_xor(den, m);
        }
        const int pb = pass & 1;
        if (l < 4) {                          // lane l == q
            part2[pb][2 * l][wv]     = n0;
            part2[pb][2 * l + 1][wv] = n1;
            part2[pb][2 * l + 8][wv] = n2;
            part2[pb][2 * l + 9][wv] = n3;
            if (l == 0) part2[pb][16][wv] = den;
        }
        __syncthreads();                      // BARRIERS 2,3

        const float* po = &part2[pb][oo][0];
        const float* pd = &part2[pb][16][0];
        float nf = 0.f, df = 0.f;
#pragma unroll
        for (int w = 0; w < WPG; ++w) {
            nf += po[g2 * WPG + w];
            df += pd[g2 * WPG + w];
        }
        float s2 = nf / df;
        float ss2 = s2 * s2;
        ss2 += __shfl_xor(ss2, 1); ss2 += __shfl_xor(ss2, 2);
        ss2 += __shfl_xor(ss2, 4); ss2 += __shfl_xor(ss2, 8);
        float vv2 = s2 * (ss2 / ((1.0f + ss2) * sqrtf(ss2 + 1e-7f)));

        if (pass == 1) {                      // accumulate weights in regs
            ra += __shfl(vv2, t0); rb += __shfl(vv2, t1);
            rc += __shfl(vv2, t2); rd += __shfl(vv2, t3);
        } else {
            if ((wv == 0 || wv == WPG) && l < 16)
                out[((size_t)(b0 + g2) * CC + c) * OO + oo] = vv2;
        }
    }
}

extern "C" void kernel_launch(void* const* d_in, const int* in_sizes, int n_in,
                              void* d_out, int out_size, void* d_ws, size_t ws_size,
                              hipStream_t stream) {
    const float* x = (const float*)d_in[0];  // (B,R,I) fp32
    const float* W = (const float*)d_in[1];  // (R,C,O,I) fp32
    if (n_in >= 2 && in_sizes[0] == RR * CC * OO * II &&
        in_sizes[1] == BB * RR * II) {
        const float* tmp = x; x = W; W = tmp;
    }
    float* out = (float*)d_out;              // (B,1,C,O,1) fp32
    uint32_t* wbf = (uint32_t*)d_ws;         // 2.95 MB packed-bf16 W

    const int cvt_blocks = (int)((WSWORDS / 4 + 255) / 256);   // 720
    k_cvt<<<cvt_blocks, 256, 0, stream>>>(W, wbf);

    const size_t dyn_lds = (size_t)GG * RR * 8 * 4;   // 73,728 B
    k_caps<<<CC * (BB / GG), NT, dyn_lds, stream>>>(x, wbf, out);
}

// Round 15
// 101.918 us; speedup vs baseline: 1.3912x; 1.0814x over previous
//
#include <hip/hip_runtime.h>
#include <cstdint>

// CapsuleLayer dynamic routing: B=256, R=1152, C=10, O=16, I=8, 3 iters.
// Round 15: v_dot2_f32_bf16 phase-1 — packed operands end-to-end.
//  * r14: halving W lines gave only -3.6us (k_caps 55.7) and the cvt
//    launch (~5us) ate the bench gain. k_caps is VALU-issue + latency
//    bound now. This round cuts phase-1 VALU ~42 -> ~24 ops/iter:
//    pre-pass packs BOTH W and x to bf16 pairs; dots use CDNA VOP3P
//    v_dot2_f32_bf16 (D = A.lo*B.lo + A.hi*B.hi + C) chained 4x per
//    8-dot, consuming packed words directly (no unpack at all).
//    x loads: 4 float4 -> 2 uint4 (8 -> 2 lines).
//  * Phase-1 loop unroll 4 (VGPR=32, cap 85; alloca-free so no spill).
//  * Phase 2 = r14 verbatim (weights stay fp32: rounding them to bf16
//    would push logit error ~0.08 -> absmax near threshold).
//  * ws layout: W-packed [737280 words] then x-packed [1179648 words],
//    7.7MB total. absmax expected ~0.010-0.013 (x bf16 rounding) vs
//    threshold 0.0172.
#define BB 256
#define RR 1152
#define CC 10
#define OO 16
#define II 8
#define NT 768
#define GG 2
#define NWAVE (NT / 64)    // 12
#define WPG (NWAVE / GG)   // 6 waves per g in phase 2
#define LOG2E 1.4426950408889634f
#define WSWORDS ((size_t)RR * CC * (OO * II / 2))   // 737,280 packed words
#define XWORDS  ((size_t)BB * RR * (II / 2))        // 1,179,648 packed words

typedef float float2v __attribute__((ext_vector_type(2)));

__device__ __forceinline__ void unpack2(uint32_t pk, float& lo, float& hi) {
    union { uint32_t i; float f; } a, b;
    a.i = pk << 16; b.i = pk & 0xffff0000u;
    lo = a.f; hi = b.f;
}
// v + (value from lane l^1), DPP quad_perm [1,0,3,2] — VALU pipe
__device__ __forceinline__ float qpadd1(float v) {
    int o = __builtin_amdgcn_mov_dpp(__float_as_int(v), 0xB1, 0xF, 0xF, true);
    return v + __int_as_float(o);
}
// v + (value from lane l^2), DPP quad_perm [2,3,0,1]
__device__ __forceinline__ float qpadd2(float v) {
    int o = __builtin_amdgcn_mov_dpp(__float_as_int(v), 0x4E, 0xF, 0xF, true);
    return v + __int_as_float(o);
}
// packed bf16 pair from two f32 (hardware RNE), one instruction
__device__ __forceinline__ uint32_t cvtpk(float lo, float hi) {
    uint32_t r;
    asm("v_cvt_pk_bf16_f32 %0, %1, %2" : "=v"(r) : "v"(lo), "v"(hi));
    return r;
}
// packed-bf16 dot2 with accumulate: D = a.lo*b.lo + a.hi*b.hi + c
__device__ __forceinline__ float dot2bf(uint32_t a, uint32_t b, float c) {
    float d;
    asm("v_dot2_f32_bf16 %0, %1, %2, %3" : "=v"(d) : "v"(a), "v"(b), "v"(c));
    return d;
}
#if __has_builtin(__builtin_amdgcn_exp2f)
#define EXP2(x) __builtin_amdgcn_exp2f(x)
#else
#define EXP2(x) __expf((x) * 0.6931471805599453f)
#endif
#define LD4(P) (*reinterpret_cast<const float4*>(P))

// 8-element dot on packed quads: 4 chained dot2
#define DOT8P(WQ, XQ, OUT)                                                    \
  do {                                                                        \
    float a_ = dot2bf(WQ.x, XQ.x, 0.0f);                                      \
    a_ = dot2bf(WQ.y, XQ.y, a_);                                              \
    a_ = dot2bf(WQ.z, XQ.z, a_);                                              \
    OUT = dot2bf(WQ.w, XQ.w, a_);                                             \
  } while (0)

// ---- pre-pass: W and x fp32 -> packed bf16 pairs (same element order) ----
__global__ __launch_bounds__(256)
void k_cvt(const float* __restrict__ Wf, const float* __restrict__ xf,
           uint32_t* __restrict__ wbf, uint32_t* __restrict__ xpk) {
    size_t tid = (size_t)blockIdx.x * 256 + threadIdx.x;   // quad index
    if (tid < WSWORDS / 4) {
        float4 a = LD4(Wf + 8 * tid);
        float4 b = LD4(Wf + 8 * tid + 4);
        uint4 r;
        r.x = cvtpk(a.x, a.y); r.y = cvtpk(a.z, a.w);
        r.z = cvtpk(b.x, b.y); r.w = cvtpk(b.z, b.w);
        *reinterpret_cast<uint4*>(wbf + 4 * tid) = r;
    }
    if (tid < XWORDS / 4) {
        float4 a = LD4(xf + 8 * tid);
        float4 b = LD4(xf + 8 * tid + 4);
        uint4 r;
        r.x = cvtpk(a.x, a.y); r.y = cvtpk(a.z, a.w);
        r.z = cvtpk(b.x, b.y); r.w = cvtpk(b.z, b.w);
        *reinterpret_cast<uint4*>(xpk + 4 * tid) = r;
    }
}

__global__ __launch_bounds__(NT, 6)
void k_caps(const uint32_t* __restrict__ xpk, const uint32_t* __restrict__ wb,
            float* __restrict__ out) {
    extern __shared__ uint32_t u2[];          // [GG][RR][8] packed bf16 pairs
    __shared__ float p0s[NWAVE][8][2][GG];    // [wv][p][slot o>>3][g]
    __shared__ float part2[2][17][NWAVE];

    const int t = threadIdx.x;
    const int c  = blockIdx.x / (BB / GG);    // c-major: blocks share W-slice
    const int b0 = (blockIdx.x % (BB / GG)) * GG;
    const int wv = t >> 6, l = t & 63;
    const int rg = t >> 3, p = t & 7;         // phase 1: 96 r-rows x 8 lanes

    uint32_t* uA = u2;                        // batch b0
    uint32_t* uB = u2 + (size_t)RR * 8;       // batch b0+1
    uint32_t* wrA = uA + (size_t)rg * 8 + p;  // word p of row rg
    uint32_t* wrB = uB + (size_t)rg * 8 + p;

    // ---- Phase 1: lane p computes u[o=p], u[o=p+8] for both g ----
    float s00 = 0.f, s01 = 0.f, s10 = 0.f, s11 = 0.f;
#pragma unroll 4
    for (int it = 0; it < 12; ++it) {
        const int r = it * 96 + rg;
        const uint32_t* wrow = wb + ((size_t)r * CC + c) * 64 + 4 * p;
        uint4 wq0 = *reinterpret_cast<const uint4*>(wrow);        // o = p
        uint4 wq1 = *reinterpret_cast<const uint4*>(wrow + 32);   // o = p+8
        const uint32_t* xp = xpk + ((size_t)b0 * RR + r) * 4;
        uint4 xq0 = *reinterpret_cast<const uint4*>(xp);              // g=0
        uint4 xq1 = *reinterpret_cast<const uint4*>(xp + (size_t)RR * 4); // g=1
        float d0, d1, e0, e1;
        DOT8P(wq0, xq0, d0);                  // g=0, o=p
        DOT8P(wq1, xq0, d1);                  // g=0, o=p+8
        DOT8P(wq0, xq1, e0);                  // g=1, o=p
        DOT8P(wq1, xq1, e1);                  // g=1, o=p+8
        s00 += d0; s01 += d1; s10 += e0; s11 += e1;
        wrA[(size_t)it * 768] = cvtpk(d0, d1);      // word p = (u[p], u[p+8])
        wrB[(size_t)it * 768] = cvtpk(e0, e1);
    }
    // pass-0 reduce over the 8 row-lanes sharing p (masks 8,16,32)
#pragma unroll
    for (int m = 8; m < 64; m <<= 1) {
        s00 += __shfl_xor(s00, m); s01 += __shfl_xor(s01, m);
        s10 += __shfl_xor(s10, m); s11 += __shfl_xor(s11, m);
    }
    if (l < 8) {                              // lane l == p
        p0s[wv][l][0][0] = s00; p0s[wv][l][1][0] = s01;
        p0s[wv][l][0][1] = s10; p0s[wv][l][1][1] = s11;
    }
    __syncthreads();                          // BARRIER 1 of 3

    // ---- Phase-2 mapping (r12/r14 structure) ----
    const int g2 = wv / WPG;                  // waves 0-5: g=0, 6-11: g=1
    const int wv6 = wv - g2 * WPG;
    const uint32_t* ug = g2 ? uB : uA;
    const int q = l & 3;                      // owns o in {2q,2q+1,2q+8,2q+9}
    const int rl = l >> 2;
    const int rbase = wv6 * 16 + rl;
    const uint32_t* rp = ug + (size_t)rbase * 8 + 2 * q;

    const int oo = l & 15;                    // lane's redundant-squash o
    const int gb = l & 48;
    const int t0 = gb | (2 * q), t1 = gb | (2 * q + 1);
    const int t2 = gb | (2 * q + 8), t3 = gb | (2 * q + 9);

    // ---- v0 computed redundantly by all lanes ----
    float ra, rb, rc, rd;
    {
        float sv = 0.f;
#pragma unroll
        for (int w = 0; w < NWAVE; ++w) sv += p0s[w][oo & 7][oo >> 3][g2];
        sv *= (1.0f / RR);                    // softmax(0) = 1/R
        float ss = sv * sv;
        ss += __shfl_xor(ss, 1); ss += __shfl_xor(ss, 2);
        ss += __shfl_xor(ss, 4); ss += __shfl_xor(ss, 8);
        float vv = sv * (ss / ((1.0f + ss) * sqrtf(ss + 1e-7f)));
        ra = __shfl(vv, t0); rb = __shfl(vv, t1);
        rc = __shfl(vv, t2); rd = __shfl(vv, t3);
    }

    // ---- Phase 2: passes 1 and 2; one barrier each ----
#pragma unroll
    for (int pass = 1; pass < 3; ++pass) {
        const float2v WQA = { ra * LOG2E, rc * LOG2E };
        const float2v WQB = { rb * LOG2E, rd * LOG2E };
        float2v N0 = { 0.f, 0.f }, N1 = { 0.f, 0.f };
        float den = 0.f;

#pragma unroll
        for (int it2 = 0; it2 < 12; ++it2) {
            uint2 pp = *reinterpret_cast<const uint2*>(rp + (size_t)it2 * 768);
            float a_, b_, c_, d_;
            unpack2(pp.x, a_, b_);            // (u[2q],   u[2q+8])
            unpack2(pp.y, c_, d_);            // (u[2q+1], u[2q+9])
            float2v P0 = { a_, b_ };
            float2v P1 = { c_, d_ };
            float2v lg2 = __builtin_elementwise_fma(P0, WQA, P1 * WQB);
            float lg = lg2.x + lg2.y;
            lg = qpadd1(lg);                  // + lane^1 (quad partial)
            lg = qpadd2(lg);                  // + lane^2: full 16-o logit
            float e = EXP2(lg);               // == exp(raw logit)
            den += e;                         // same-q lanes: distinct r's
            float2v E2 = { e, e };
            N0 = __builtin_elementwise_fma(E2, P0, N0);
            N1 = __builtin_elementwise_fma(E2, P1, N1);
        }

        float n0 = N0.x, n2 = N0.y, n1 = N1.x, n3 = N1.y;
#pragma unroll
        for (int m = 4; m < 64; m <<= 1) {    // 16 same-q lanes: distinct rows
            n0 += __shfl_xor(n0, m); n1 += __shfl_xor(n1, m);
            n2 += __shfl_xor(n2, m); n3 += __shfl_xor(n3, m);
            den += __shfl_xor(den, m);
        }
        const int pb = pass & 1;
        if (l < 4) {                          // lane l == q
            part2[pb][2 * l][wv]     = n0;
            part2[pb][2 * l + 1][wv] = n1;
            part2[pb][2 * l + 8][wv] = n2;
            part2[pb][2 * l + 9][wv] = n3;
            if (l == 0) part2[pb][16][wv] = den;
        }
        __syncthreads();                      // BARRIERS 2,3

        const float* po = &part2[pb][oo][0];
        const float* pd = &part2[pb][16][0];
        float nf = 0.f, df = 0.f;
#pragma unroll
        for (int w = 0; w < WPG; ++w) {
            nf += po[g2 * WPG + w];
            df += pd[g2 * WPG + w];
        }
        float s2 = nf / df;
        float ss2 = s2 * s2;
        ss2 += __shfl_xor(ss2, 1); ss2 += __shfl_xor(ss2, 2);
        ss2 += __shfl_xor(ss2, 4); ss2 += __shfl_xor(ss2, 8);
        float vv2 = s2 * (ss2 / ((1.0f + ss2) * sqrtf(ss2 + 1e-7f)));

        if (pass == 1) {                      // accumulate weights in regs
            ra += __shfl(vv2, t0); rb += __shfl(vv2, t1);
            rc += __shfl(vv2, t2); rd += __shfl(vv2, t3);
        } else {
            if ((wv == 0 || wv == WPG) && l < 16)
                out[((size_t)(b0 + g2) * CC + c) * OO + oo] = vv2;
        }
    }
}

extern "C" void kernel_launch(void* const* d_in, const int* in_sizes, int n_in,
                              void* d_out, int out_size, void* d_ws, size_t ws_size,
                              hipStream_t stream) {
    const float* x = (const float*)d_in[0];  // (B,R,I) fp32
    const float* W = (const float*)d_in[1];  // (R,C,O,I) fp32
    if (n_in >= 2 && in_sizes[0] == RR * CC * OO * II &&
        in_sizes[1] == BB * RR * II) {
        const float* tmp = x; x = W; W = tmp;
    }
    float* out = (float*)d_out;              // (B,1,C,O,1) fp32
    uint32_t* wbf = (uint32_t*)d_ws;         // packed-bf16 W (2.95 MB)
    uint32_t* xpk = wbf + WSWORDS;           // packed-bf16 x (4.72 MB)

    const int cvt_blocks = (int)((XWORDS / 4 + 255) / 256);   // 1152
    k_cvt<<<cvt_blocks, 256, 0, stream>>>(W, x, wbf, xpk);

    const size_t dyn_lds = (size_t)GG * RR * 8 * 4;   // 73,728 B
    k_caps<<<CC * (BB / GG), NT, dyn_lds, stream>>>(xpk, wbf, out);
}